// Round 10
// baseline (182.006 us; speedup 1.0000x reference)
//
#include <hip/hip_runtime.h>
#include <stdint.h>
#include <stddef.h>

#define N_SENT 100000
#define N_TYPE 10000
#define NEDGE  640000
#define NROWS  (N_SENT + N_TYPE)
#define MAXDEG 256    // LDS cache per wave; Poisson(64): P(deg>256) ~ 0. Fallback exists.
#define HB     256    // histogram chunks; 256 * 2500 == NEDGE exactly
#define HCHUNK (NEDGE / HB)   // 2500
#define NBUCK  8              // source buckets == XCD count
#define BROWS  (N_SENT / NBUCK)   // 12500 rows/bucket; bf16 slice = 3.2 MB < 4 MB L2/XCD

__device__ __forceinline__ float bf2f(uint32_t lo16) {
    return __builtin_bit_cast(float, lo16 << 16);
}
__device__ __forceinline__ uint32_t f2bf(float f) {
    uint32_t u = __builtin_bit_cast(uint32_t, f);
    return (u + 0x7fffu + ((u >> 16) & 1u)) >> 16;
}

// Inline per-wave dtype probe: bf16 pairs have bf16-sane exponents in the low halfword.
__device__ __forceinline__ bool detect_bf16(const uint32_t* __restrict__ h) {
    uint32_t u = h[threadIdx.x & 63];
    uint32_t e_lo = (u >> 7) & 0xffu;
    int ok = (e_lo >= 100u && e_lo <= 140u) ? 1 : 0;
    unsigned long long m = __ballot(ok);
    return __popcll(m) >= 48;
}

// ---- scores: streaming matvec (round-5 version, verified) ----
#define SC_BLOCKS 6875   // 6875*256 = 1,760,000 = NROWS*16 (bf16 chunks) = (NROWS*32)/2 (f32)

__global__ __launch_bounds__(256) void scores_k(const void* __restrict__ h_sent,
                                                const void* __restrict__ h_type,
                                                const void* __restrict__ attn_w,
                                                float* __restrict__ s_src,
                                                float* __restrict__ s_dst) {
    int t    = blockIdx.x * 256 + (int)threadIdx.x;
    int lane = threadIdx.x & 63;
    bool isbf = detect_bf16((const uint32_t*)h_sent);
    if (isbf) {
        uint4 wsv = ((const uint4*)attn_w)[lane & 15];
        uint4 wtv = ((const uint4*)attn_w)[16 + (lane & 15)];
        bool isSrc = t < N_SENT * 16;
        const uint4* p = isSrc ? (const uint4*)h_sent + t
                               : (const uint4*)h_type + (t - N_SENT * 16);
        uint4 h = *p;
        uint4 wv = isSrc ? wsv : wtv;
        float s = bf2f(h.x & 0xffffu) * bf2f(wv.x & 0xffffu)
                + bf2f(h.x >> 16)     * bf2f(wv.x >> 16)
                + bf2f(h.y & 0xffffu) * bf2f(wv.y & 0xffffu)
                + bf2f(h.y >> 16)     * bf2f(wv.y >> 16)
                + bf2f(h.z & 0xffffu) * bf2f(wv.z & 0xffffu)
                + bf2f(h.z >> 16)     * bf2f(wv.z >> 16)
                + bf2f(h.w & 0xffffu) * bf2f(wv.w & 0xffffu)
                + bf2f(h.w >> 16)     * bf2f(wv.w >> 16);
        s += __shfl_xor(s, 1, 64);
        s += __shfl_xor(s, 2, 64);
        s += __shfl_xor(s, 4, 64);
        s += __shfl_xor(s, 8, 64);
        if ((lane & 15) == 0) {
            int row = t >> 4;
            if (row < N_SENT) s_src[row] = s;
            else              s_dst[row - N_SENT] = s;
        }
    } else {
        float4 wsv = ((const float4*)attn_w)[lane & 31];
        float4 wtv = ((const float4*)attn_w)[32 + (lane & 31)];
        const int HALF = NROWS * 16;
        int it0 = t, it1 = t + HALF;
        bool s0 = it0 < N_SENT * 32, s1 = it1 < N_SENT * 32;
        const float4* p0 = s0 ? (const float4*)h_sent + it0
                              : (const float4*)h_type + (it0 - N_SENT * 32);
        const float4* p1 = s1 ? (const float4*)h_sent + it1
                              : (const float4*)h_type + (it1 - N_SENT * 32);
        float4 h0 = *p0;
        float4 h1 = *p1;
        __builtin_amdgcn_sched_barrier(0);
        float4 w0 = s0 ? wsv : wtv, w1 = s1 ? wsv : wtv;
        float a = h0.x * w0.x + h0.y * w0.y + h0.z * w0.z + h0.w * w0.w;
        float b = h1.x * w1.x + h1.y * w1.y + h1.z * w1.z + h1.w * w1.w;
        a += __shfl_xor(a, 1, 64);  b += __shfl_xor(b, 1, 64);
        a += __shfl_xor(a, 2, 64);  b += __shfl_xor(b, 2, 64);
        a += __shfl_xor(a, 4, 64);  b += __shfl_xor(b, 4, 64);
        a += __shfl_xor(a, 8, 64);  b += __shfl_xor(b, 8, 64);
        a += __shfl_xor(a, 16, 64); b += __shfl_xor(b, 16, 64);
        if ((lane & 31) == 0) {
            int r0 = it0 >> 5, r1 = it1 >> 5;
            if (r0 < N_SENT) s_src[r0] = a; else s_dst[r0 - N_SENT] = a;
            if (r1 < N_SENT) s_src[r1] = b; else s_dst[r1 - N_SENT] = b;
        }
    }
}

// ---- count: 256 blocks x 2500-edge chunk ----
__global__ __launch_bounds__(256) void count_k(const int* __restrict__ dst,
                                               uint32_t* __restrict__ count2) {
    __shared__ uint32_t hist[N_TYPE];   // 40 KB
    int cb = blockIdx.x;
    int t  = threadIdx.x;
#pragma unroll
    for (int i = 0; i < 40; i++) {
        int idx = i * 256 + t;
        if (idx < N_TYPE) hist[idx] = 0u;
    }
    __syncthreads();
    int e0 = cb * HCHUNK;
    int dv[10];
#pragma unroll
    for (int k = 0; k < 10; k++) {
        int i = k * 256 + t;
        dv[k] = dst[e0 + (i < HCHUNK ? i : HCHUNK - 1)];
    }
    __builtin_amdgcn_sched_barrier(0);
#pragma unroll
    for (int k = 0; k < 10; k++) {
        int i = k * 256 + t;
        if (i < HCHUNK) atomicAdd(&hist[dv[k]], 1u);
    }
    __syncthreads();
    uint4* row = (uint4*)(count2 + (size_t)cb * N_TYPE);
#pragma unroll
    for (int i = 0; i < 10; i++) {
        int idx = i * 256 + t;
        if (idx < N_TYPE / 4) row[idx] = ((const uint4*)hist)[idx];
    }
}

// ---- column exclusive-scan, 8-way parallel ----
__global__ __launch_bounds__(256) void sumscan_k(uint32_t* __restrict__ count2,
                                                 uint32_t* __restrict__ total) {
    int tid  = blockIdx.x * 256 + (int)threadIdx.x;
    int lane = threadIdx.x & 63;
    int bin  = tid >> 3;
    int sub  = tid & 7;
    if (bin >= N_TYPE) return;
    uint32_t vals[32];
#pragma unroll
    for (int c = 0; c < 32; c++)
        vals[c] = count2[(size_t)(sub * 32 + c) * N_TYPE + bin];
    __builtin_amdgcn_sched_barrier(0);
    uint32_t lsum = 0;
#pragma unroll
    for (int c = 0; c < 32; c++) lsum += vals[c];
    uint32_t incl = lsum;
#pragma unroll
    for (int off = 1; off < 8; off <<= 1) {
        uint32_t v = __shfl_up(incl, off, 64);
        if ((lane & 7) >= off) incl += v;
    }
    uint32_t run = incl - lsum;
#pragma unroll
    for (int c = 0; c < 32; c++) {
        uint32_t v = vals[c];
        count2[(size_t)(sub * 32 + c) * N_TYPE + bin] = run;
        run += v;
    }
    if (sub == 7) total[bin] = incl;
}

// ---- single-block exclusive scan of totals -> offsets[N_TYPE+1] ----
__global__ __launch_bounds__(1024) void scan_k(const uint32_t* __restrict__ total,
                                               uint32_t* __restrict__ offsets) {
    const int CH = 10;
    int t = threadIdx.x, lane = t & 63, wv = t >> 6;
    int base = t * CH;
    uint32_t local[CH];
    uint32_t tsum = 0;
#pragma unroll
    for (int i = 0; i < CH; i++) {
        int idx = base + i;
        uint32_t c = (idx < N_TYPE) ? total[idx] : 0u;
        local[i] = c;
        tsum += c;
    }
    uint32_t orig = tsum;
#pragma unroll
    for (int off = 1; off < 64; off <<= 1) {
        uint32_t v = __shfl_up(tsum, off, 64);
        if (lane >= off) tsum += v;
    }
    __shared__ uint32_t wsum[16];
    if (lane == 63) wsum[wv] = tsum;
    __syncthreads();
    if (wv == 0 && lane < 16) {
        uint32_t u = wsum[lane], o = u;
#pragma unroll
        for (int off = 1; off < 16; off <<= 1) {
            uint32_t v = __shfl_up(u, off, 64);
            if (lane >= off) u += v;
        }
        wsum[lane] = u - o;
    }
    __syncthreads();
    uint32_t run = wsum[wv] + tsum - orig;
#pragma unroll
    for (int i = 0; i < CH; i++) {
        int idx = base + i;
        if (idx < N_TYPE) {
            offsets[idx] = run;
            run += local[i];
        } else if (idx == N_TYPE) {
            offsets[idx] = run;
        }
    }
}

// ---- fill: 256 blocks; LDS cursors; LDS-atomic scatter ----
__global__ __launch_bounds__(256) void fill_k(const int* __restrict__ src,
                                              const int* __restrict__ dst,
                                              const uint32_t* __restrict__ offsets,
                                              const uint32_t* __restrict__ base2,
                                              uint32_t* __restrict__ edge_src) {
    __shared__ uint32_t cur[N_TYPE];
    int cb = blockIdx.x;
    int t  = threadIdx.x;
    const uint32_t* brow = base2 + (size_t)cb * N_TYPE;
#pragma unroll
    for (int i = 0; i < 10; i++) {
        int idx = i * 256 + t;
        if (idx < N_TYPE / 4) {
            uint4 o = ((const uint4*)offsets)[idx];
            uint4 b = ((const uint4*)brow)[idx];
            uint4 c; c.x = o.x + b.x; c.y = o.y + b.y; c.z = o.z + b.z; c.w = o.w + b.w;
            ((uint4*)cur)[idx] = c;
        }
    }
    __syncthreads();
    int e0 = cb * HCHUNK;
    int dv[10], sv[10];
#pragma unroll
    for (int k = 0; k < 10; k++) {
        int i = k * 256 + t;
        int e = e0 + (i < HCHUNK ? i : HCHUNK - 1);
        dv[k] = dst[e];
        sv[k] = src[e];
    }
    __builtin_amdgcn_sched_barrier(0);
#pragma unroll
    for (int k = 0; k < 10; k++) {
        int i = k * 256 + t;
        if (i < HCHUNK) {
            uint32_t pos = atomicAdd(&cur[dv[k]], 1u);
            edge_src[pos] = (uint32_t)sv[k];
        }
    }
}

// ==== partitioned agg, bf16 only ====
// bucket = blockIdx & 7 -> XCD via round-robin dispatch; each bucket's source slice
// (12500 rows x 256 B = 3.2 MB) is L2-resident per XCD -> captures the 6.4x source reuse.
// Per (dest,bucket): local max m_p, denom_p, f32 partial vector (LSE-mergeable).
__global__ __launch_bounds__(256) void pagg_k(const void* __restrict__ h_sent,
                                              const float* __restrict__ s_src,
                                              const float* __restrict__ s_dst,
                                              const uint32_t* __restrict__ offsets,
                                              const uint32_t* __restrict__ edge_src,
                                              float* __restrict__ part_m,
                                              float* __restrict__ part_d,
                                              float* __restrict__ part_v) {
    bool isbf = detect_bf16((const uint32_t*)h_sent);
    if (!isbf) return;
    __shared__ float    sc[4][MAXDEG];
    __shared__ uint32_t ss[4][MAXDEG];
    uint32_t p     = blockIdx.x & 7;                       // bucket == XCD (heuristic)
    int      wslot = threadIdx.x >> 6;
    int      lane  = threadIdx.x & 63;
    int      j     = (int)(blockIdx.x >> 3) * 4 + wslot;   // grid = 2500*8 -> j < 10000
    uint32_t beg = offsets[j];
    uint32_t deg = offsets[j + 1] - beg;
    float    sdj = s_dst[j];
    float*    mysc = sc[wslot];
    uint32_t* myss = ss[wslot];
    uint32_t pidx = (uint32_t)j * NBUCK + p;
    float m = -INFINITY;
    uint32_t cnt = 0;
    bool fits = deg <= MAXDEG;
    if (fits) {
        // compact in-bucket edges into LDS (ballot prefix), track local max
        for (uint32_t k0 = 0; k0 < deg; k0 += 64) {
            uint32_t k = k0 + (uint32_t)lane;
            bool act = k < deg;
            uint32_t s = 0; float v = 0.0f; bool inb = false;
            if (act) {
                s = edge_src[beg + k];
                inb = (s / BROWS) == p;
                if (inb) {
                    v = s_src[s] + sdj;
                    v = v > 0.0f ? v : 0.01f * v;
                    m = fmaxf(m, v);
                }
            }
            unsigned long long msk = __ballot(inb ? 1 : 0);
            uint32_t pos = cnt + (uint32_t)__popcll(msk & ((1ull << lane) - 1ull));
            if (inb) { mysc[pos] = v; myss[pos] = s; }
            cnt += (uint32_t)__popcll(msk);
        }
    } else {
        // huge-degree safety path: filtered lane-strided max (no compaction)
        for (uint32_t k = lane; k < deg; k += 64) {
            uint32_t s = edge_src[beg + k];
            if ((s / BROWS) == p) {
                float v = s_src[s] + sdj;
                v = v > 0.0f ? v : 0.01f * v;
                m = fmaxf(m, v);
            }
        }
    }
#pragma unroll
    for (int off = 32; off; off >>= 1) m = fmaxf(m, __shfl_xor(m, off, 64));
    if (m == -INFINITY) {                 // no edges in this bucket
        if (lane == 0) part_d[pidx] = 0.0f;
        return;
    }
    float denom = 0.0f, a0 = 0.0f, a1 = 0.0f;
    const uint32_t* hp = (const uint32_t*)h_sent;
    if (fits) {
        uint32_t k = 0;
        for (; k + 8 <= cnt; k += 8) {
            uint32_t sv[8]; float vv[8]; uint32_t gv[8];
#pragma unroll
            for (int i = 0; i < 8; i++) { sv[i] = myss[k + i]; vv[i] = mysc[k + i]; }
#pragma unroll
            for (int i = 0; i < 8; i++) gv[i] = hp[(size_t)sv[i] * 64 + lane];
#pragma unroll
            for (int i = 0; i < 8; i++) {
                float w = __expf(vv[i] - m);
                denom += w;
                a0 += w * bf2f(gv[i] & 0xffffu);
                a1 += w * bf2f(gv[i] >> 16);
            }
        }
        for (; k < cnt; ++k) {
            float w = __expf(mysc[k] - m);
            uint32_t g = hp[(size_t)myss[k] * 64 + lane];
            denom += w;
            a0 += w * bf2f(g & 0xffffu);
            a1 += w * bf2f(g >> 16);
        }
    } else {
        for (uint32_t k = 0; k < deg; ++k) {       // wave-uniform serial, filtered
            uint32_t s = edge_src[beg + k];
            if ((s / BROWS) == p) {
                float v = s_src[s] + sdj; v = v > 0.0f ? v : 0.01f * v;
                float w = __expf(v - m);
                uint32_t g = hp[(size_t)s * 64 + lane];
                denom += w;
                a0 += w * bf2f(g & 0xffffu);
                a1 += w * bf2f(g >> 16);
            }
        }
    }
    if (lane == 0) { part_m[pidx] = m; part_d[pidx] = denom; }
    float* pv = part_v + ((size_t)pidx * 64 + (size_t)lane) * 2;
    __builtin_nontemporal_store(a0, pv);         // bypass L2: keep the source slice resident
    __builtin_nontemporal_store(a1, pv + 1);
}

// ==== combine partials per dest (bf16 only): log-sum-exp merge of 8 buckets ====
__global__ __launch_bounds__(256) void pcomb_k(const void* __restrict__ h_sent,
                                               const void* __restrict__ h_type,
                                               const float* __restrict__ part_m,
                                               const float* __restrict__ part_d,
                                               const float* __restrict__ part_v,
                                               void* __restrict__ out) {
    bool isbf = detect_bf16((const uint32_t*)h_sent);
    if (!isbf) return;
    int j    = (blockIdx.x * 256 + (int)threadIdx.x) >> 6;
    int lane = threadIdx.x & 63;
    if (j >= N_TYPE) return;
    float dd[NBUCK], md[NBUCK];
#pragma unroll
    for (int p = 0; p < NBUCK; p++) dd[p] = part_d[j * NBUCK + p];
#pragma unroll
    for (int p = 0; p < NBUCK; p++) md[p] = part_m[j * NBUCK + p];
    float M = -INFINITY;
    bool any = false;
#pragma unroll
    for (int p = 0; p < NBUCK; p++)
        if (dd[p] > 0.0f) { M = fmaxf(M, md[p]); any = true; }
    if (!any) {   // isolated node keeps its input feature
        ((uint32_t*)out)[(size_t)j * 64 + lane] =
            ((const uint32_t*)h_type)[(size_t)j * 64 + lane];
        return;
    }
    float vx[NBUCK], vy[NBUCK];
#pragma unroll
    for (int p = 0; p < NBUCK; p++) {
        const float* q = part_v + ((size_t)(j * NBUCK + p) * 64 + (size_t)lane) * 2;
        vx[p] = __builtin_nontemporal_load(q);
        vy[p] = __builtin_nontemporal_load(q + 1);
    }
    float D = 0.0f, a0 = 0.0f, a1 = 0.0f;
#pragma unroll
    for (int p = 0; p < NBUCK; p++) {
        bool ok = dd[p] > 0.0f;
        float w = ok ? __expf(md[p] - M) : 0.0f;
        D += (ok ? dd[p] : 0.0f) * w;
        a0 += w * (ok ? vx[p] : 0.0f);     // select, not mult: guards NaN garbage
        a1 += w * (ok ? vy[p] : 0.0f);
    }
    float inv = 1.0f / D;
    ((uint32_t*)out)[(size_t)j * 64 + lane] = f2bf(a0 * inv) | (f2bf(a1 * inv) << 16);
}

// ---- old agg (round-8 best): f32 path + fallback when workspace too small ----
__global__ __launch_bounds__(256) void agg_k(const void* __restrict__ h_sent,
                                             const void* __restrict__ h_type,
                                             const float* __restrict__ s_src,
                                             const float* __restrict__ s_dst,
                                             const uint32_t* __restrict__ offsets,
                                             const uint32_t* __restrict__ edge_src,
                                             void* __restrict__ out,
                                             int use_part) {
    __shared__ float    sc[4][MAXDEG];
    __shared__ uint32_t ss[4][MAXDEG];
    bool isbf = detect_bf16((const uint32_t*)h_sent);
    if (use_part && isbf) return;        // bf16 handled by pagg+pcomb (uniform exit)
    int j     = (blockIdx.x * 256 + threadIdx.x) >> 6;
    int wslot = threadIdx.x >> 6;
    int lane  = threadIdx.x & 63;
    bool valid = j < N_TYPE;
    uint32_t beg = 0, deg = 0;
    float sdj = 0.0f;
    if (valid) {
        beg = offsets[j];
        deg = offsets[j + 1] - beg;
        sdj = s_dst[j];
    }
    float*    mysc = sc[wslot];
    uint32_t* myss = ss[wslot];
    bool fits = (deg <= MAXDEG);
    float m = -INFINITY;
    for (uint32_t k = lane; k < deg; k += 64) {
        uint32_t s = edge_src[beg + k];
        float v = s_src[s] + sdj;
        v = v > 0.0f ? v : 0.01f * v;
        if (fits) { mysc[k] = v; myss[k] = s; }
        m = fmaxf(m, v);
    }
#pragma unroll
    for (int off = 32; off; off >>= 1) m = fmaxf(m, __shfl_xor(m, off, 64));
    __syncthreads();
    if (!valid) return;
    if (deg == 0) {
        if (isbf) ((uint32_t*)out)[(size_t)j * 64 + lane] =
                      ((const uint32_t*)h_type)[(size_t)j * 64 + lane];
        else      ((float2*)out)[(size_t)j * 64 + lane] =
                      ((const float2*)h_type)[(size_t)j * 64 + lane];
        return;
    }
    float denom = 0.0f, a0 = 0.0f, a1 = 0.0f;
    if (isbf) {
        const uint32_t* hp = (const uint32_t*)h_sent;
        uint32_t k = 0;
        if (fits) {
            for (; k + 16 <= deg; k += 16) {
                uint32_t sv[16]; float vv[16]; uint32_t gv[16];
#pragma unroll
                for (int i = 0; i < 16; i++) { sv[i] = myss[k + i]; vv[i] = mysc[k + i]; }
#pragma unroll
                for (int i = 0; i < 16; i++) gv[i] = hp[(size_t)sv[i] * 64 + lane];
#pragma unroll
                for (int i = 0; i < 16; i++) {
                    float w = __expf(vv[i] - m);
                    denom += w;
                    a0 += w * bf2f(gv[i] & 0xffffu);
                    a1 += w * bf2f(gv[i] >> 16);
                }
            }
            for (; k + 8 <= deg; k += 8) {
                uint32_t sv[8]; float vv[8]; uint32_t gv[8];
#pragma unroll
                for (int i = 0; i < 8; i++) { sv[i] = myss[k + i]; vv[i] = mysc[k + i]; }
#pragma unroll
                for (int i = 0; i < 8; i++) gv[i] = hp[(size_t)sv[i] * 64 + lane];
#pragma unroll
                for (int i = 0; i < 8; i++) {
                    float w = __expf(vv[i] - m);
                    denom += w;
                    a0 += w * bf2f(gv[i] & 0xffffu);
                    a1 += w * bf2f(gv[i] >> 16);
                }
            }
            for (; k < deg; ++k) {
                float w = __expf(mysc[k] - m);
                uint32_t g = hp[(size_t)myss[k] * 64 + lane];
                denom += w;
                a0 += w * bf2f(g & 0xffffu);
                a1 += w * bf2f(g >> 16);
            }
        } else {
            for (k = 0; k < deg; ++k) {
                uint32_t s = edge_src[beg + k];
                float v = s_src[s] + sdj; v = v > 0.0f ? v : 0.01f * v;
                float w = __expf(v - m);
                uint32_t g = hp[(size_t)s * 64 + lane];
                denom += w;
                a0 += w * bf2f(g & 0xffffu);
                a1 += w * bf2f(g >> 16);
            }
        }
        float inv = 1.0f / denom;
        ((uint32_t*)out)[(size_t)j * 64 + lane] = f2bf(a0 * inv) | (f2bf(a1 * inv) << 16);
    } else {
        const float2* hp = (const float2*)h_sent;
        uint32_t k = 0;
        if (fits) {
            for (; k + 16 <= deg; k += 16) {
                uint32_t sv[16]; float vv[16]; float2 gv[16];
#pragma unroll
                for (int i = 0; i < 16; i++) { sv[i] = myss[k + i]; vv[i] = mysc[k + i]; }
#pragma unroll
                for (int i = 0; i < 16; i++) gv[i] = hp[(size_t)sv[i] * 64 + lane];
#pragma unroll
                for (int i = 0; i < 16; i++) {
                    float w = __expf(vv[i] - m);
                    denom += w;
                    a0 += w * gv[i].x;
                    a1 += w * gv[i].y;
                }
            }
            for (; k + 8 <= deg; k += 8) {
                uint32_t sv[8]; float vv[8]; float2 gv[8];
#pragma unroll
                for (int i = 0; i < 8; i++) { sv[i] = myss[k + i]; vv[i] = mysc[k + i]; }
#pragma unroll
                for (int i = 0; i < 8; i++) gv[i] = hp[(size_t)sv[i] * 64 + lane];
#pragma unroll
                for (int i = 0; i < 8; i++) {
                    float w = __expf(vv[i] - m);
                    denom += w;
                    a0 += w * gv[i].x;
                    a1 += w * gv[i].y;
                }
            }
            for (; k < deg; ++k) {
                float w = __expf(mysc[k] - m);
                float2 g = hp[(size_t)myss[k] * 64 + lane];
                denom += w;
                a0 += w * g.x;
                a1 += w * g.y;
            }
        } else {
            for (k = 0; k < deg; ++k) {
                uint32_t s = edge_src[beg + k];
                float v = s_src[s] + sdj; v = v > 0.0f ? v : 0.01f * v;
                float w = __expf(v - m);
                float2 g = hp[(size_t)s * 64 + lane];
                denom += w;
                a0 += w * g.x;
                a1 += w * g.y;
            }
        }
        float inv = 1.0f / denom;
        ((float2*)out)[(size_t)j * 64 + lane] = make_float2(a0 * inv, a1 * inv);
    }
}

static inline size_t align_up(size_t x) { return (x + 255) & ~(size_t)255; }

extern "C" void kernel_launch(void* const* d_in, const int* in_sizes, int n_in,
                              void* d_out, int out_size, void* d_ws, size_t ws_size,
                              hipStream_t stream) {
    const void* h_sent = d_in[0];
    const void* h_type = d_in[1];
    const void* attn_w = d_in[2];
    const int* src_idx = (const int*)d_in[3];
    const int* dst_idx = (const int*)d_in[4];

    char* w = (char*)d_ws;
    float*    s_src     = (float*)w;    w += align_up((size_t)N_SENT * 4);
    float*    s_dst     = (float*)w;    w += align_up((size_t)N_TYPE * 4);
    uint32_t* count2    = (uint32_t*)w; w += align_up((size_t)HB * N_TYPE * 4);  // 10.24 MB
    uint32_t* total     = (uint32_t*)w; w += align_up((size_t)N_TYPE * 4);
    uint32_t* offsets   = (uint32_t*)w; w += align_up((size_t)(N_TYPE + 1) * 4);
    uint32_t* edge_src  = (uint32_t*)w; w += align_up((size_t)NEDGE * 4);
    float*    part_m    = (float*)w;    w += align_up((size_t)N_TYPE * NBUCK * 4);
    float*    part_d    = (float*)w;    w += align_up((size_t)N_TYPE * NBUCK * 4);
    float*    part_v    = (float*)w;    w += align_up((size_t)N_TYPE * NBUCK * 128 * 4); // 41 MB
    size_t need = (size_t)(w - (char*)d_ws);
    int use_part = (need <= ws_size) ? 1 : 0;

    scores_k<<<SC_BLOCKS, 256, 0, stream>>>(h_sent, h_type, attn_w, s_src, s_dst);
    count_k<<<HB, 256, 0, stream>>>(dst_idx, count2);
    sumscan_k<<<(N_TYPE * 8 + 255) / 256, 256, 0, stream>>>(count2, total);
    scan_k<<<1, 1024, 0, stream>>>(total, offsets);
    fill_k<<<HB, 256, 0, stream>>>(src_idx, dst_idx, offsets, count2, edge_src);
    if (use_part) {
        pagg_k<<<(N_TYPE / 4) * NBUCK, 256, 0, stream>>>(h_sent, s_src, s_dst,
                                                         offsets, edge_src,
                                                         part_m, part_d, part_v);
        pcomb_k<<<(N_TYPE + 3) / 4, 256, 0, stream>>>(h_sent, h_type,
                                                      part_m, part_d, part_v, d_out);
    }
    agg_k<<<(N_TYPE + 3) / 4, 256, 0, stream>>>(h_sent, h_type, s_src, s_dst,
                                                offsets, edge_src, d_out, use_part);
}

// Round 11
// 180.902 us; speedup vs baseline: 1.0061x; 1.0061x over previous
//
#include <hip/hip_runtime.h>
#include <stdint.h>
#include <stddef.h>

#define N_SENT 100000
#define N_TYPE 10000
#define NEDGE  640000
#define NROWS  (N_SENT + N_TYPE)
#define MAXDEG 256    // LDS cache per wave; Poisson(64): P(deg>256) ~ 0. Fallback exists.
#define HB     256    // histogram chunks; 256 * 2500 == NEDGE exactly
#define HCHUNK (NEDGE / HB)   // 2500
#define NBUCK  8              // source buckets == XCD count
#define BROWS  (N_SENT / NBUCK)   // 12500 rows/bucket; bf16 slice = 3.2 MB < 4 MB L2/XCD

__device__ __forceinline__ float bf2f(uint32_t lo16) {
    return __builtin_bit_cast(float, lo16 << 16);
}
__device__ __forceinline__ uint32_t f2bf(float f) {
    uint32_t u = __builtin_bit_cast(uint32_t, f);
    return (u + 0x7fffu + ((u >> 16) & 1u)) >> 16;
}

// Inline per-wave dtype probe: bf16 pairs have bf16-sane exponents in the low halfword.
__device__ __forceinline__ bool detect_bf16(const uint32_t* __restrict__ h) {
    uint32_t u = h[threadIdx.x & 63];
    uint32_t e_lo = (u >> 7) & 0xffu;
    int ok = (e_lo >= 100u && e_lo <= 140u) ? 1 : 0;
    unsigned long long m = __ballot(ok);
    return __popcll(m) >= 48;
}

// ---- scores: streaming matvec (round-5 version, verified) ----
#define SC_BLOCKS 6875   // 6875*256 = 1,760,000 = NROWS*16 (bf16 chunks) = (NROWS*32)/2 (f32)

__global__ __launch_bounds__(256) void scores_k(const void* __restrict__ h_sent,
                                                const void* __restrict__ h_type,
                                                const void* __restrict__ attn_w,
                                                float* __restrict__ s_src,
                                                float* __restrict__ s_dst) {
    int t    = blockIdx.x * 256 + (int)threadIdx.x;
    int lane = threadIdx.x & 63;
    bool isbf = detect_bf16((const uint32_t*)h_sent);
    if (isbf) {
        uint4 wsv = ((const uint4*)attn_w)[lane & 15];
        uint4 wtv = ((const uint4*)attn_w)[16 + (lane & 15)];
        bool isSrc = t < N_SENT * 16;
        const uint4* p = isSrc ? (const uint4*)h_sent + t
                               : (const uint4*)h_type + (t - N_SENT * 16);
        uint4 h = *p;
        uint4 wv = isSrc ? wsv : wtv;
        float s = bf2f(h.x & 0xffffu) * bf2f(wv.x & 0xffffu)
                + bf2f(h.x >> 16)     * bf2f(wv.x >> 16)
                + bf2f(h.y & 0xffffu) * bf2f(wv.y & 0xffffu)
                + bf2f(h.y >> 16)     * bf2f(wv.y >> 16)
                + bf2f(h.z & 0xffffu) * bf2f(wv.z & 0xffffu)
                + bf2f(h.z >> 16)     * bf2f(wv.z >> 16)
                + bf2f(h.w & 0xffffu) * bf2f(wv.w & 0xffffu)
                + bf2f(h.w >> 16)     * bf2f(wv.w >> 16);
        s += __shfl_xor(s, 1, 64);
        s += __shfl_xor(s, 2, 64);
        s += __shfl_xor(s, 4, 64);
        s += __shfl_xor(s, 8, 64);
        if ((lane & 15) == 0) {
            int row = t >> 4;
            if (row < N_SENT) s_src[row] = s;
            else              s_dst[row - N_SENT] = s;
        }
    } else {
        float4 wsv = ((const float4*)attn_w)[lane & 31];
        float4 wtv = ((const float4*)attn_w)[32 + (lane & 31)];
        const int HALF = NROWS * 16;
        int it0 = t, it1 = t + HALF;
        bool s0 = it0 < N_SENT * 32, s1 = it1 < N_SENT * 32;
        const float4* p0 = s0 ? (const float4*)h_sent + it0
                              : (const float4*)h_type + (it0 - N_SENT * 32);
        const float4* p1 = s1 ? (const float4*)h_sent + it1
                              : (const float4*)h_type + (it1 - N_SENT * 32);
        float4 h0 = *p0;
        float4 h1 = *p1;
        __builtin_amdgcn_sched_barrier(0);
        float4 w0 = s0 ? wsv : wtv, w1 = s1 ? wsv : wtv;
        float a = h0.x * w0.x + h0.y * w0.y + h0.z * w0.z + h0.w * w0.w;
        float b = h1.x * w1.x + h1.y * w1.y + h1.z * w1.z + h1.w * w1.w;
        a += __shfl_xor(a, 1, 64);  b += __shfl_xor(b, 1, 64);
        a += __shfl_xor(a, 2, 64);  b += __shfl_xor(b, 2, 64);
        a += __shfl_xor(a, 4, 64);  b += __shfl_xor(b, 4, 64);
        a += __shfl_xor(a, 8, 64);  b += __shfl_xor(b, 8, 64);
        a += __shfl_xor(a, 16, 64); b += __shfl_xor(b, 16, 64);
        if ((lane & 31) == 0) {
            int r0 = it0 >> 5, r1 = it1 >> 5;
            if (r0 < N_SENT) s_src[r0] = a; else s_dst[r0 - N_SENT] = a;
            if (r1 < N_SENT) s_src[r1] = b; else s_dst[r1 - N_SENT] = b;
        }
    }
}

// ---- count: 256 blocks x 2500-edge chunk ----
__global__ __launch_bounds__(256) void count_k(const int* __restrict__ dst,
                                               uint32_t* __restrict__ count2) {
    __shared__ uint32_t hist[N_TYPE];   // 40 KB
    int cb = blockIdx.x;
    int t  = threadIdx.x;
#pragma unroll
    for (int i = 0; i < 40; i++) {
        int idx = i * 256 + t;
        if (idx < N_TYPE) hist[idx] = 0u;
    }
    __syncthreads();
    int e0 = cb * HCHUNK;
    int dv[10];
#pragma unroll
    for (int k = 0; k < 10; k++) {
        int i = k * 256 + t;
        dv[k] = dst[e0 + (i < HCHUNK ? i : HCHUNK - 1)];
    }
    __builtin_amdgcn_sched_barrier(0);
#pragma unroll
    for (int k = 0; k < 10; k++) {
        int i = k * 256 + t;
        if (i < HCHUNK) atomicAdd(&hist[dv[k]], 1u);
    }
    __syncthreads();
    uint4* row = (uint4*)(count2 + (size_t)cb * N_TYPE);
#pragma unroll
    for (int i = 0; i < 10; i++) {
        int idx = i * 256 + t;
        if (idx < N_TYPE / 4) row[idx] = ((const uint4*)hist)[idx];
    }
}

// ---- column exclusive-scan, 8-way parallel ----
__global__ __launch_bounds__(256) void sumscan_k(uint32_t* __restrict__ count2,
                                                 uint32_t* __restrict__ total) {
    int tid  = blockIdx.x * 256 + (int)threadIdx.x;
    int lane = threadIdx.x & 63;
    int bin  = tid >> 3;
    int sub  = tid & 7;
    if (bin >= N_TYPE) return;
    uint32_t vals[32];
#pragma unroll
    for (int c = 0; c < 32; c++)
        vals[c] = count2[(size_t)(sub * 32 + c) * N_TYPE + bin];
    __builtin_amdgcn_sched_barrier(0);
    uint32_t lsum = 0;
#pragma unroll
    for (int c = 0; c < 32; c++) lsum += vals[c];
    uint32_t incl = lsum;
#pragma unroll
    for (int off = 1; off < 8; off <<= 1) {
        uint32_t v = __shfl_up(incl, off, 64);
        if ((lane & 7) >= off) incl += v;
    }
    uint32_t run = incl - lsum;
#pragma unroll
    for (int c = 0; c < 32; c++) {
        uint32_t v = vals[c];
        count2[(size_t)(sub * 32 + c) * N_TYPE + bin] = run;
        run += v;
    }
    if (sub == 7) total[bin] = incl;
}

// ---- single-block exclusive scan of totals -> offsets[N_TYPE+1] ----
__global__ __launch_bounds__(1024) void scan_k(const uint32_t* __restrict__ total,
                                               uint32_t* __restrict__ offsets) {
    const int CH = 10;
    int t = threadIdx.x, lane = t & 63, wv = t >> 6;
    int base = t * CH;
    uint32_t local[CH];
    uint32_t tsum = 0;
#pragma unroll
    for (int i = 0; i < CH; i++) {
        int idx = base + i;
        uint32_t c = (idx < N_TYPE) ? total[idx] : 0u;
        local[i] = c;
        tsum += c;
    }
    uint32_t orig = tsum;
#pragma unroll
    for (int off = 1; off < 64; off <<= 1) {
        uint32_t v = __shfl_up(tsum, off, 64);
        if (lane >= off) tsum += v;
    }
    __shared__ uint32_t wsum[16];
    if (lane == 63) wsum[wv] = tsum;
    __syncthreads();
    if (wv == 0 && lane < 16) {
        uint32_t u = wsum[lane], o = u;
#pragma unroll
        for (int off = 1; off < 16; off <<= 1) {
            uint32_t v = __shfl_up(u, off, 64);
            if (lane >= off) u += v;
        }
        wsum[lane] = u - o;
    }
    __syncthreads();
    uint32_t run = wsum[wv] + tsum - orig;
#pragma unroll
    for (int i = 0; i < CH; i++) {
        int idx = base + i;
        if (idx < N_TYPE) {
            offsets[idx] = run;
            run += local[i];
        } else if (idx == N_TYPE) {
            offsets[idx] = run;
        }
    }
}

// ---- fill: 256 blocks; LDS cursors; LDS-atomic scatter ----
__global__ __launch_bounds__(256) void fill_k(const int* __restrict__ src,
                                              const int* __restrict__ dst,
                                              const uint32_t* __restrict__ offsets,
                                              const uint32_t* __restrict__ base2,
                                              uint32_t* __restrict__ edge_src) {
    __shared__ uint32_t cur[N_TYPE];
    int cb = blockIdx.x;
    int t  = threadIdx.x;
    const uint32_t* brow = base2 + (size_t)cb * N_TYPE;
#pragma unroll
    for (int i = 0; i < 10; i++) {
        int idx = i * 256 + t;
        if (idx < N_TYPE / 4) {
            uint4 o = ((const uint4*)offsets)[idx];
            uint4 b = ((const uint4*)brow)[idx];
            uint4 c; c.x = o.x + b.x; c.y = o.y + b.y; c.z = o.z + b.z; c.w = o.w + b.w;
            ((uint4*)cur)[idx] = c;
        }
    }
    __syncthreads();
    int e0 = cb * HCHUNK;
    int dv[10], sv[10];
#pragma unroll
    for (int k = 0; k < 10; k++) {
        int i = k * 256 + t;
        int e = e0 + (i < HCHUNK ? i : HCHUNK - 1);
        dv[k] = dst[e];
        sv[k] = src[e];
    }
    __builtin_amdgcn_sched_barrier(0);
#pragma unroll
    for (int k = 0; k < 10; k++) {
        int i = k * 256 + t;
        if (i < HCHUNK) {
            uint32_t pos = atomicAdd(&cur[dv[k]], 1u);
            edge_src[pos] = (uint32_t)sv[k];
        }
    }
}

// ==== partitioned agg, bf16 only ====
// bucket = blockIdx & 7 -> XCD via round-robin dispatch; each bucket's 3.2 MB source
// slice is L2-resident per XCD -> captures the 6.4x source reuse at L2 speed instead of
// the measured ~3.3 TB/s L3 random-granule ceiling.
// Per (dest,bucket): f32 local max + denom, bf16-packed normalized partial vector.
__global__ __launch_bounds__(256) void pagg_k(const void* __restrict__ h_sent,
                                              const float* __restrict__ s_src,
                                              const float* __restrict__ s_dst,
                                              const uint32_t* __restrict__ offsets,
                                              const uint32_t* __restrict__ edge_src,
                                              float* __restrict__ part_m,
                                              float* __restrict__ part_d,
                                              uint32_t* __restrict__ part_v) {
    bool isbf = detect_bf16((const uint32_t*)h_sent);
    if (!isbf) return;
    __shared__ float    sc[4][MAXDEG];
    __shared__ uint32_t ss[4][MAXDEG];
    uint32_t p     = blockIdx.x & 7;                       // bucket == XCD (heuristic)
    int      wslot = threadIdx.x >> 6;
    int      lane  = threadIdx.x & 63;
    int      j     = (int)(blockIdx.x >> 3) * 4 + wslot;   // grid = 2500*8 -> j < 10000
    uint32_t beg = offsets[j];
    uint32_t deg = offsets[j + 1] - beg;
    float    sdj = s_dst[j];
    float*    mysc = sc[wslot];
    uint32_t* myss = ss[wslot];
    uint32_t pidx = (uint32_t)j * NBUCK + p;
    float m = -INFINITY;
    uint32_t cnt = 0;
    bool fits = deg <= MAXDEG;
    if (fits) {
        // compact in-bucket edges into LDS (ballot prefix), track local max
        for (uint32_t k0 = 0; k0 < deg; k0 += 64) {
            uint32_t k = k0 + (uint32_t)lane;
            bool act = k < deg;
            uint32_t s = 0; float v = 0.0f; bool inb = false;
            if (act) {
                s = edge_src[beg + k];
                inb = (s / BROWS) == p;
                if (inb) {
                    v = s_src[s] + sdj;
                    v = v > 0.0f ? v : 0.01f * v;
                    m = fmaxf(m, v);
                }
            }
            unsigned long long msk = __ballot(inb ? 1 : 0);
            uint32_t pos = cnt + (uint32_t)__popcll(msk & ((1ull << lane) - 1ull));
            if (inb) { mysc[pos] = v; myss[pos] = s; }
            cnt += (uint32_t)__popcll(msk);
        }
    } else {
        // huge-degree safety path: filtered lane-strided max (no compaction)
        for (uint32_t k = lane; k < deg; k += 64) {
            uint32_t s = edge_src[beg + k];
            if ((s / BROWS) == p) {
                float v = s_src[s] + sdj;
                v = v > 0.0f ? v : 0.01f * v;
                m = fmaxf(m, v);
            }
        }
    }
#pragma unroll
    for (int off = 32; off; off >>= 1) m = fmaxf(m, __shfl_xor(m, off, 64));
    if (m == -INFINITY) {                 // no edges in this bucket
        if (lane == 0) part_d[pidx] = 0.0f;
        return;
    }
    float denom = 0.0f, a0 = 0.0f, a1 = 0.0f;
    const uint32_t* hp = (const uint32_t*)h_sent;
    if (fits) {
        uint32_t k = 0;
        for (; k + 8 <= cnt; k += 8) {
            uint32_t sv[8]; float vv[8]; uint32_t gv[8];
#pragma unroll
            for (int i = 0; i < 8; i++) { sv[i] = myss[k + i]; vv[i] = mysc[k + i]; }
#pragma unroll
            for (int i = 0; i < 8; i++) gv[i] = hp[(size_t)sv[i] * 64 + lane];
#pragma unroll
            for (int i = 0; i < 8; i++) {
                float w = __expf(vv[i] - m);
                denom += w;
                a0 += w * bf2f(gv[i] & 0xffffu);
                a1 += w * bf2f(gv[i] >> 16);
            }
        }
        for (; k < cnt; ++k) {
            float w = __expf(mysc[k] - m);
            uint32_t g = hp[(size_t)myss[k] * 64 + lane];
            denom += w;
            a0 += w * bf2f(g & 0xffffu);
            a1 += w * bf2f(g >> 16);
        }
    } else {
        for (uint32_t k = 0; k < deg; ++k) {       // wave-uniform serial, filtered
            uint32_t s = edge_src[beg + k];
            if ((s / BROWS) == p) {
                float v = s_src[s] + sdj; v = v > 0.0f ? v : 0.01f * v;
                float w = __expf(v - m);
                uint32_t g = hp[(size_t)s * 64 + lane];
                denom += w;
                a0 += w * bf2f(g & 0xffffu);
                a1 += w * bf2f(g >> 16);
            }
        }
    }
    if (lane == 0) { part_m[pidx] = m; part_d[pidx] = denom; }
    // normalized bf16 partial (O(1) magnitude -> |err| <= 2^-9 relative); nontemporal so
    // the partial stream does not evict the L2-resident source slice.
    float inv = 1.0f / denom;
    uint32_t packed = f2bf(a0 * inv) | (f2bf(a1 * inv) << 16);
    __builtin_nontemporal_store(packed, part_v + (size_t)pidx * 64 + (size_t)lane);
}

// ==== combine partials per dest (bf16 only): log-sum-exp merge of 8 buckets ====
__global__ __launch_bounds__(256) void pcomb_k(const void* __restrict__ h_sent,
                                               const void* __restrict__ h_type,
                                               const float* __restrict__ part_m,
                                               const float* __restrict__ part_d,
                                               const uint32_t* __restrict__ part_v,
                                               void* __restrict__ out) {
    bool isbf = detect_bf16((const uint32_t*)h_sent);
    if (!isbf) return;
    int j    = (blockIdx.x * 256 + (int)threadIdx.x) >> 6;
    int lane = threadIdx.x & 63;
    float dd[NBUCK], md[NBUCK];
#pragma unroll
    for (int p = 0; p < NBUCK; p++) dd[p] = part_d[j * NBUCK + p];
#pragma unroll
    for (int p = 0; p < NBUCK; p++) md[p] = part_m[j * NBUCK + p];
    float M = -INFINITY;
    bool any = false;
#pragma unroll
    for (int p = 0; p < NBUCK; p++)
        if (dd[p] > 0.0f) { M = fmaxf(M, md[p]); any = true; }
    if (!any) {   // isolated node keeps its input feature
        ((uint32_t*)out)[(size_t)j * 64 + lane] =
            ((const uint32_t*)h_type)[(size_t)j * 64 + lane];
        return;
    }
    uint32_t gv[NBUCK];
#pragma unroll
    for (int p = 0; p < NBUCK; p++)
        gv[p] = __builtin_nontemporal_load(part_v + ((size_t)(j * NBUCK + p) * 64
                                                     + (size_t)lane));
    float D = 0.0f, a0 = 0.0f, a1 = 0.0f;
#pragma unroll
    for (int p = 0; p < NBUCK; p++) {
        bool ok = dd[p] > 0.0f;
        float W = ok ? dd[p] * __expf(md[p] - M) : 0.0f;   // softmax mass of bucket p
        D += W;
        a0 += W * (ok ? bf2f(gv[p] & 0xffffu) : 0.0f);     // select guards garbage
        a1 += W * (ok ? bf2f(gv[p] >> 16)     : 0.0f);
    }
    float inv = 1.0f / D;
    ((uint32_t*)out)[(size_t)j * 64 + lane] = f2bf(a0 * inv) | (f2bf(a1 * inv) << 16);
}

// ---- old agg (round-8 best): f32 path + fallback when workspace too small ----
__global__ __launch_bounds__(256) void agg_k(const void* __restrict__ h_sent,
                                             const void* __restrict__ h_type,
                                             const float* __restrict__ s_src,
                                             const float* __restrict__ s_dst,
                                             const uint32_t* __restrict__ offsets,
                                             const uint32_t* __restrict__ edge_src,
                                             void* __restrict__ out,
                                             int use_part) {
    __shared__ float    sc[4][MAXDEG];
    __shared__ uint32_t ss[4][MAXDEG];
    bool isbf = detect_bf16((const uint32_t*)h_sent);
    if (use_part && isbf) return;        // bf16 handled by pagg+pcomb (uniform exit)
    int j     = (blockIdx.x * 256 + threadIdx.x) >> 6;
    int wslot = threadIdx.x >> 6;
    int lane  = threadIdx.x & 63;
    bool valid = j < N_TYPE;
    uint32_t beg = 0, deg = 0;
    float sdj = 0.0f;
    if (valid) {
        beg = offsets[j];
        deg = offsets[j + 1] - beg;
        sdj = s_dst[j];
    }
    float*    mysc = sc[wslot];
    uint32_t* myss = ss[wslot];
    bool fits = (deg <= MAXDEG);
    float m = -INFINITY;
    for (uint32_t k = lane; k < deg; k += 64) {
        uint32_t s = edge_src[beg + k];
        float v = s_src[s] + sdj;
        v = v > 0.0f ? v : 0.01f * v;
        if (fits) { mysc[k] = v; myss[k] = s; }
        m = fmaxf(m, v);
    }
#pragma unroll
    for (int off = 32; off; off >>= 1) m = fmaxf(m, __shfl_xor(m, off, 64));
    __syncthreads();
    if (!valid) return;
    if (deg == 0) {
        if (isbf) ((uint32_t*)out)[(size_t)j * 64 + lane] =
                      ((const uint32_t*)h_type)[(size_t)j * 64 + lane];
        else      ((float2*)out)[(size_t)j * 64 + lane] =
                      ((const float2*)h_type)[(size_t)j * 64 + lane];
        return;
    }
    float denom = 0.0f, a0 = 0.0f, a1 = 0.0f;
    if (isbf) {
        const uint32_t* hp = (const uint32_t*)h_sent;
        uint32_t k = 0;
        if (fits) {
            for (; k + 16 <= deg; k += 16) {
                uint32_t sv[16]; float vv[16]; uint32_t gv[16];
#pragma unroll
                for (int i = 0; i < 16; i++) { sv[i] = myss[k + i]; vv[i] = mysc[k + i]; }
#pragma unroll
                for (int i = 0; i < 16; i++) gv[i] = hp[(size_t)sv[i] * 64 + lane];
#pragma unroll
                for (int i = 0; i < 16; i++) {
                    float w = __expf(vv[i] - m);
                    denom += w;
                    a0 += w * bf2f(gv[i] & 0xffffu);
                    a1 += w * bf2f(gv[i] >> 16);
                }
            }
            for (; k + 8 <= deg; k += 8) {
                uint32_t sv[8]; float vv[8]; uint32_t gv[8];
#pragma unroll
                for (int i = 0; i < 8; i++) { sv[i] = myss[k + i]; vv[i] = mysc[k + i]; }
#pragma unroll
                for (int i = 0; i < 8; i++) gv[i] = hp[(size_t)sv[i] * 64 + lane];
#pragma unroll
                for (int i = 0; i < 8; i++) {
                    float w = __expf(vv[i] - m);
                    denom += w;
                    a0 += w * bf2f(gv[i] & 0xffffu);
                    a1 += w * bf2f(gv[i] >> 16);
                }
            }
            for (; k < deg; ++k) {
                float w = __expf(mysc[k] - m);
                uint32_t g = hp[(size_t)myss[k] * 64 + lane];
                denom += w;
                a0 += w * bf2f(g & 0xffffu);
                a1 += w * bf2f(g >> 16);
            }
        } else {
            for (k = 0; k < deg; ++k) {
                uint32_t s = edge_src[beg + k];
                float v = s_src[s] + sdj; v = v > 0.0f ? v : 0.01f * v;
                float w = __expf(v - m);
                uint32_t g = hp[(size_t)s * 64 + lane];
                denom += w;
                a0 += w * bf2f(g & 0xffffu);
                a1 += w * bf2f(g >> 16);
            }
        }
        float inv = 1.0f / denom;
        ((uint32_t*)out)[(size_t)j * 64 + lane] = f2bf(a0 * inv) | (f2bf(a1 * inv) << 16);
    } else {
        const float2* hp = (const float2*)h_sent;
        uint32_t k = 0;
        if (fits) {
            for (; k + 16 <= deg; k += 16) {
                uint32_t sv[16]; float vv[16]; float2 gv[16];
#pragma unroll
                for (int i = 0; i < 16; i++) { sv[i] = myss[k + i]; vv[i] = mysc[k + i]; }
#pragma unroll
                for (int i = 0; i < 16; i++) gv[i] = hp[(size_t)sv[i] * 64 + lane];
#pragma unroll
                for (int i = 0; i < 16; i++) {
                    float w = __expf(vv[i] - m);
                    denom += w;
                    a0 += w * gv[i].x;
                    a1 += w * gv[i].y;
                }
            }
            for (; k + 8 <= deg; k += 8) {
                uint32_t sv[8]; float vv[8]; float2 gv[8];
#pragma unroll
                for (int i = 0; i < 8; i++) { sv[i] = myss[k + i]; vv[i] = mysc[k + i]; }
#pragma unroll
                for (int i = 0; i < 8; i++) gv[i] = hp[(size_t)sv[i] * 64 + lane];
#pragma unroll
                for (int i = 0; i < 8; i++) {
                    float w = __expf(vv[i] - m);
                    denom += w;
                    a0 += w * gv[i].x;
                    a1 += w * gv[i].y;
                }
            }
            for (; k < deg; ++k) {
                float w = __expf(mysc[k] - m);
                float2 g = hp[(size_t)myss[k] * 64 + lane];
                denom += w;
                a0 += w * g.x;
                a1 += w * g.y;
            }
        } else {
            for (k = 0; k < deg; ++k) {
                uint32_t s = edge_src[beg + k];
                float v = s_src[s] + sdj; v = v > 0.0f ? v : 0.01f * v;
                float w = __expf(v - m);
                float2 g = hp[(size_t)s * 64 + lane];
                denom += w;
                a0 += w * g.x;
                a1 += w * g.y;
            }
        }
        float inv = 1.0f / denom;
        ((float2*)out)[(size_t)j * 64 + lane] = make_float2(a0 * inv, a1 * inv);
    }
}

static inline size_t align_up(size_t x) { return (x + 255) & ~(size_t)255; }

extern "C" void kernel_launch(void* const* d_in, const int* in_sizes, int n_in,
                              void* d_out, int out_size, void* d_ws, size_t ws_size,
                              hipStream_t stream) {
    const void* h_sent = d_in[0];
    const void* h_type = d_in[1];
    const void* attn_w = d_in[2];
    const int* src_idx = (const int*)d_in[3];
    const int* dst_idx = (const int*)d_in[4];

    // Live-set buffers first; then a REGION aliased between count2 (dead after fill_k)
    // and the partial buffers (born at pagg_k). Sequential stream -> no race.
    char* w = (char*)d_ws;
    float*    s_src     = (float*)w;    w += align_up((size_t)N_SENT * 4);
    float*    s_dst     = (float*)w;    w += align_up((size_t)N_TYPE * 4);
    uint32_t* total     = (uint32_t*)w; w += align_up((size_t)N_TYPE * 4);
    uint32_t* offsets   = (uint32_t*)w; w += align_up((size_t)(N_TYPE + 1) * 4);
    uint32_t* edge_src  = (uint32_t*)w; w += align_up((size_t)NEDGE * 4);
    char* region = w;
    uint32_t* count2 = (uint32_t*)region;                       // 10.24 MB during CSR build
    size_t count2_sz = align_up((size_t)HB * N_TYPE * 4);
    float*    part_m = (float*)region;
    float*    part_d = (float*)(region + align_up((size_t)N_TYPE * NBUCK * 4));
    uint32_t* part_v = (uint32_t*)(region + 2 * align_up((size_t)N_TYPE * NBUCK * 4));
    size_t part_sz = 2 * align_up((size_t)N_TYPE * NBUCK * 4)
                   + align_up((size_t)N_TYPE * NBUCK * 64 * 4);  // 21.1 MB (bf16 packed)
    size_t base = (size_t)(region - (char*)d_ws);
    size_t region_sz = count2_sz > part_sz ? count2_sz : part_sz;
    int use_part = (base + region_sz <= ws_size) ? 1 : 0;       // ~24.3 MB total

    scores_k<<<SC_BLOCKS, 256, 0, stream>>>(h_sent, h_type, attn_w, s_src, s_dst);
    count_k<<<HB, 256, 0, stream>>>(dst_idx, count2);
    sumscan_k<<<(N_TYPE * 8 + 255) / 256, 256, 0, stream>>>(count2, total);
    scan_k<<<1, 1024, 0, stream>>>(total, offsets);
    fill_k<<<HB, 256, 0, stream>>>(src_idx, dst_idx, offsets, count2, edge_src);
    if (use_part) {
        pagg_k<<<(N_TYPE / 4) * NBUCK, 256, 0, stream>>>(h_sent, s_src, s_dst,
                                                         offsets, edge_src,
                                                         part_m, part_d, part_v);
        pcomb_k<<<(N_TYPE + 3) / 4, 256, 0, stream>>>(h_sent, h_type,
                                                      part_m, part_d, part_v, d_out);
    }
    agg_k<<<(N_TYPE + 3) / 4, 256, 0, stream>>>(h_sent, h_type, s_src, s_dst,
                                                offsets, edge_src, d_out, use_part);
}

// Round 12
// 179.854 us; speedup vs baseline: 1.0120x; 1.0058x over previous
//
#include <hip/hip_runtime.h>
#include <stdint.h>
#include <stddef.h>

#define N_SENT 100000
#define N_TYPE 10000
#define NEDGE  640000
#define NROWS  (N_SENT + N_TYPE)
#define MAXDEG 256    // LDS cache per wave; Poisson(64): P(deg>256) ~ 0. Fallback exists.
#define HB     256    // histogram chunks; 256 * 2500 == NEDGE exactly
#define HCHUNK (NEDGE / HB)   // 2500
#define NBUCK  4              // source buckets; bucket = blockIdx&3, XCD = blockIdx%8
#define BROWS  (N_SENT / NBUCK)   // 25000 rows/bucket; bf16 slice = 6.4 MB vs 4 MB L2/XCD

__device__ __forceinline__ float bf2f(uint32_t lo16) {
    return __builtin_bit_cast(float, lo16 << 16);
}
__device__ __forceinline__ uint32_t f2bf(float f) {
    uint32_t u = __builtin_bit_cast(uint32_t, f);
    return (u + 0x7fffu + ((u >> 16) & 1u)) >> 16;
}

// Inline per-wave dtype probe: bf16 pairs have bf16-sane exponents in the low halfword.
__device__ __forceinline__ bool detect_bf16(const uint32_t* __restrict__ h) {
    uint32_t u = h[threadIdx.x & 63];
    uint32_t e_lo = (u >> 7) & 0xffu;
    int ok = (e_lo >= 100u && e_lo <= 140u) ? 1 : 0;
    unsigned long long m = __ballot(ok);
    return __popcll(m) >= 48;
}

// ---- scores: streaming matvec (round-5 version, verified) ----
#define SC_BLOCKS 6875   // 6875*256 = 1,760,000 = NROWS*16 (bf16 chunks) = (NROWS*32)/2 (f32)

__global__ __launch_bounds__(256) void scores_k(const void* __restrict__ h_sent,
                                                const void* __restrict__ h_type,
                                                const void* __restrict__ attn_w,
                                                float* __restrict__ s_src,
                                                float* __restrict__ s_dst) {
    int t    = blockIdx.x * 256 + (int)threadIdx.x;
    int lane = threadIdx.x & 63;
    bool isbf = detect_bf16((const uint32_t*)h_sent);
    if (isbf) {
        uint4 wsv = ((const uint4*)attn_w)[lane & 15];
        uint4 wtv = ((const uint4*)attn_w)[16 + (lane & 15)];
        bool isSrc = t < N_SENT * 16;
        const uint4* p = isSrc ? (const uint4*)h_sent + t
                               : (const uint4*)h_type + (t - N_SENT * 16);
        uint4 h = *p;
        uint4 wv = isSrc ? wsv : wtv;
        float s = bf2f(h.x & 0xffffu) * bf2f(wv.x & 0xffffu)
                + bf2f(h.x >> 16)     * bf2f(wv.x >> 16)
                + bf2f(h.y & 0xffffu) * bf2f(wv.y & 0xffffu)
                + bf2f(h.y >> 16)     * bf2f(wv.y >> 16)
                + bf2f(h.z & 0xffffu) * bf2f(wv.z & 0xffffu)
                + bf2f(h.z >> 16)     * bf2f(wv.z >> 16)
                + bf2f(h.w & 0xffffu) * bf2f(wv.w & 0xffffu)
                + bf2f(h.w >> 16)     * bf2f(wv.w >> 16);
        s += __shfl_xor(s, 1, 64);
        s += __shfl_xor(s, 2, 64);
        s += __shfl_xor(s, 4, 64);
        s += __shfl_xor(s, 8, 64);
        if ((lane & 15) == 0) {
            int row = t >> 4;
            if (row < N_SENT) s_src[row] = s;
            else              s_dst[row - N_SENT] = s;
        }
    } else {
        float4 wsv = ((const float4*)attn_w)[lane & 31];
        float4 wtv = ((const float4*)attn_w)[32 + (lane & 31)];
        const int HALF = NROWS * 16;
        int it0 = t, it1 = t + HALF;
        bool s0 = it0 < N_SENT * 32, s1 = it1 < N_SENT * 32;
        const float4* p0 = s0 ? (const float4*)h_sent + it0
                              : (const float4*)h_type + (it0 - N_SENT * 32);
        const float4* p1 = s1 ? (const float4*)h_sent + it1
                              : (const float4*)h_type + (it1 - N_SENT * 32);
        float4 h0 = *p0;
        float4 h1 = *p1;
        __builtin_amdgcn_sched_barrier(0);
        float4 w0 = s0 ? wsv : wtv, w1 = s1 ? wsv : wtv;
        float a = h0.x * w0.x + h0.y * w0.y + h0.z * w0.z + h0.w * w0.w;
        float b = h1.x * w1.x + h1.y * w1.y + h1.z * w1.z + h1.w * w1.w;
        a += __shfl_xor(a, 1, 64);  b += __shfl_xor(b, 1, 64);
        a += __shfl_xor(a, 2, 64);  b += __shfl_xor(b, 2, 64);
        a += __shfl_xor(a, 4, 64);  b += __shfl_xor(b, 4, 64);
        a += __shfl_xor(a, 8, 64);  b += __shfl_xor(b, 8, 64);
        a += __shfl_xor(a, 16, 64); b += __shfl_xor(b, 16, 64);
        if ((lane & 31) == 0) {
            int r0 = it0 >> 5, r1 = it1 >> 5;
            if (r0 < N_SENT) s_src[r0] = a; else s_dst[r0 - N_SENT] = a;
            if (r1 < N_SENT) s_src[r1] = b; else s_dst[r1 - N_SENT] = b;
        }
    }
}

// ---- count: 256 blocks x 2500-edge chunk ----
__global__ __launch_bounds__(256) void count_k(const int* __restrict__ dst,
                                               uint32_t* __restrict__ count2) {
    __shared__ uint32_t hist[N_TYPE];   // 40 KB
    int cb = blockIdx.x;
    int t  = threadIdx.x;
#pragma unroll
    for (int i = 0; i < 40; i++) {
        int idx = i * 256 + t;
        if (idx < N_TYPE) hist[idx] = 0u;
    }
    __syncthreads();
    int e0 = cb * HCHUNK;
    int dv[10];
#pragma unroll
    for (int k = 0; k < 10; k++) {
        int i = k * 256 + t;
        dv[k] = dst[e0 + (i < HCHUNK ? i : HCHUNK - 1)];
    }
    __builtin_amdgcn_sched_barrier(0);
#pragma unroll
    for (int k = 0; k < 10; k++) {
        int i = k * 256 + t;
        if (i < HCHUNK) atomicAdd(&hist[dv[k]], 1u);
    }
    __syncthreads();
    uint4* row = (uint4*)(count2 + (size_t)cb * N_TYPE);
#pragma unroll
    for (int i = 0; i < 10; i++) {
        int idx = i * 256 + t;
        if (idx < N_TYPE / 4) row[idx] = ((const uint4*)hist)[idx];
    }
}

// ---- column exclusive-scan, 8-way parallel ----
__global__ __launch_bounds__(256) void sumscan_k(uint32_t* __restrict__ count2,
                                                 uint32_t* __restrict__ total) {
    int tid  = blockIdx.x * 256 + (int)threadIdx.x;
    int lane = threadIdx.x & 63;
    int bin  = tid >> 3;
    int sub  = tid & 7;
    if (bin >= N_TYPE) return;
    uint32_t vals[32];
#pragma unroll
    for (int c = 0; c < 32; c++)
        vals[c] = count2[(size_t)(sub * 32 + c) * N_TYPE + bin];
    __builtin_amdgcn_sched_barrier(0);
    uint32_t lsum = 0;
#pragma unroll
    for (int c = 0; c < 32; c++) lsum += vals[c];
    uint32_t incl = lsum;
#pragma unroll
    for (int off = 1; off < 8; off <<= 1) {
        uint32_t v = __shfl_up(incl, off, 64);
        if ((lane & 7) >= off) incl += v;
    }
    uint32_t run = incl - lsum;
#pragma unroll
    for (int c = 0; c < 32; c++) {
        uint32_t v = vals[c];
        count2[(size_t)(sub * 32 + c) * N_TYPE + bin] = run;
        run += v;
    }
    if (sub == 7) total[bin] = incl;
}

// ---- single-block exclusive scan of totals -> offsets[N_TYPE+1] ----
__global__ __launch_bounds__(1024) void scan_k(const uint32_t* __restrict__ total,
                                               uint32_t* __restrict__ offsets) {
    const int CH = 10;
    int t = threadIdx.x, lane = t & 63, wv = t >> 6;
    int base = t * CH;
    uint32_t local[CH];
    uint32_t tsum = 0;
#pragma unroll
    for (int i = 0; i < CH; i++) {
        int idx = base + i;
        uint32_t c = (idx < N_TYPE) ? total[idx] : 0u;
        local[i] = c;
        tsum += c;
    }
    uint32_t orig = tsum;
#pragma unroll
    for (int off = 1; off < 64; off <<= 1) {
        uint32_t v = __shfl_up(tsum, off, 64);
        if (lane >= off) tsum += v;
    }
    __shared__ uint32_t wsum[16];
    if (lane == 63) wsum[wv] = tsum;
    __syncthreads();
    if (wv == 0 && lane < 16) {
        uint32_t u = wsum[lane], o = u;
#pragma unroll
        for (int off = 1; off < 16; off <<= 1) {
            uint32_t v = __shfl_up(u, off, 64);
            if (lane >= off) u += v;
        }
        wsum[lane] = u - o;
    }
    __syncthreads();
    uint32_t run = wsum[wv] + tsum - orig;
#pragma unroll
    for (int i = 0; i < CH; i++) {
        int idx = base + i;
        if (idx < N_TYPE) {
            offsets[idx] = run;
            run += local[i];
        } else if (idx == N_TYPE) {
            offsets[idx] = run;
        }
    }
}

// ---- fill: 256 blocks; LDS cursors; LDS-atomic scatter ----
__global__ __launch_bounds__(256) void fill_k(const int* __restrict__ src,
                                              const int* __restrict__ dst,
                                              const uint32_t* __restrict__ offsets,
                                              const uint32_t* __restrict__ base2,
                                              uint32_t* __restrict__ edge_src) {
    __shared__ uint32_t cur[N_TYPE];
    int cb = blockIdx.x;
    int t  = threadIdx.x;
    const uint32_t* brow = base2 + (size_t)cb * N_TYPE;
#pragma unroll
    for (int i = 0; i < 10; i++) {
        int idx = i * 256 + t;
        if (idx < N_TYPE / 4) {
            uint4 o = ((const uint4*)offsets)[idx];
            uint4 b = ((const uint4*)brow)[idx];
            uint4 c; c.x = o.x + b.x; c.y = o.y + b.y; c.z = o.z + b.z; c.w = o.w + b.w;
            ((uint4*)cur)[idx] = c;
        }
    }
    __syncthreads();
    int e0 = cb * HCHUNK;
    int dv[10], sv[10];
#pragma unroll
    for (int k = 0; k < 10; k++) {
        int i = k * 256 + t;
        int e = e0 + (i < HCHUNK ? i : HCHUNK - 1);
        dv[k] = dst[e];
        sv[k] = src[e];
    }
    __builtin_amdgcn_sched_barrier(0);
#pragma unroll
    for (int k = 0; k < 10; k++) {
        int i = k * 256 + t;
        if (i < HCHUNK) {
            uint32_t pos = atomicAdd(&cur[dv[k]], 1u);
            edge_src[pos] = (uint32_t)sv[k];
        }
    }
}

// ==== partitioned agg, bf16 only, NBUCK=4 (fits 13.67 MB workspace) ====
// bucket = blockIdx&3; XCD = blockIdx%8 (round-robin heuristic) -> each XCD serves
// exactly one bucket (p and p+4 share slice p). 6.4 MB slice vs 4 MB L2 -> ~60% hit
// expected vs ~0% today. Partials: f32 m,d + normalized bf16-packed vector.
__global__ __launch_bounds__(256) void pagg_k(const void* __restrict__ h_sent,
                                              const float* __restrict__ s_src,
                                              const float* __restrict__ s_dst,
                                              const uint32_t* __restrict__ offsets,
                                              const uint32_t* __restrict__ edge_src,
                                              float* __restrict__ part_m,
                                              float* __restrict__ part_d,
                                              uint32_t* __restrict__ part_v) {
    bool isbf = detect_bf16((const uint32_t*)h_sent);
    if (!isbf) return;
    __shared__ float    sc[4][MAXDEG];
    __shared__ uint32_t ss[4][MAXDEG];
    uint32_t p     = blockIdx.x & 3;                       // bucket
    int      wslot = threadIdx.x >> 6;
    int      lane  = threadIdx.x & 63;
    int      j     = (int)(blockIdx.x >> 2) * 4 + wslot;   // grid = 2500*4 -> j < 10000
    uint32_t beg = offsets[j];
    uint32_t deg = offsets[j + 1] - beg;
    float    sdj = s_dst[j];
    float*    mysc = sc[wslot];
    uint32_t* myss = ss[wslot];
    uint32_t pidx = (uint32_t)j * NBUCK + p;
    float m = -INFINITY;
    uint32_t cnt = 0;
    bool fits = deg <= MAXDEG;
    if (fits) {
        // compact in-bucket edges into LDS (ballot prefix), track local max
        for (uint32_t k0 = 0; k0 < deg; k0 += 64) {
            uint32_t k = k0 + (uint32_t)lane;
            bool act = k < deg;
            uint32_t s = 0; float v = 0.0f; bool inb = false;
            if (act) {
                s = edge_src[beg + k];
                inb = (s / BROWS) == p;
                if (inb) {
                    v = s_src[s] + sdj;
                    v = v > 0.0f ? v : 0.01f * v;
                    m = fmaxf(m, v);
                }
            }
            unsigned long long msk = __ballot(inb ? 1 : 0);
            uint32_t pos = cnt + (uint32_t)__popcll(msk & ((1ull << lane) - 1ull));
            if (inb) { mysc[pos] = v; myss[pos] = s; }
            cnt += (uint32_t)__popcll(msk);
        }
    } else {
        for (uint32_t k = lane; k < deg; k += 64) {
            uint32_t s = edge_src[beg + k];
            if ((s / BROWS) == p) {
                float v = s_src[s] + sdj;
                v = v > 0.0f ? v : 0.01f * v;
                m = fmaxf(m, v);
            }
        }
    }
#pragma unroll
    for (int off = 32; off; off >>= 1) m = fmaxf(m, __shfl_xor(m, off, 64));
    if (m == -INFINITY) {                 // no edges in this bucket
        if (lane == 0) part_d[pidx] = 0.0f;
        return;
    }
    float denom = 0.0f, a0 = 0.0f, a1 = 0.0f;
    const uint32_t* hp = (const uint32_t*)h_sent;
    if (fits) {
        uint32_t k = 0;
        for (; k + 8 <= cnt; k += 8) {
            uint32_t sv[8]; float vv[8]; uint32_t gv[8];
#pragma unroll
            for (int i = 0; i < 8; i++) { sv[i] = myss[k + i]; vv[i] = mysc[k + i]; }
#pragma unroll
            for (int i = 0; i < 8; i++) gv[i] = hp[(size_t)sv[i] * 64 + lane];
#pragma unroll
            for (int i = 0; i < 8; i++) {
                float w = __expf(vv[i] - m);
                denom += w;
                a0 += w * bf2f(gv[i] & 0xffffu);
                a1 += w * bf2f(gv[i] >> 16);
            }
        }
        for (; k < cnt; ++k) {
            float w = __expf(mysc[k] - m);
            uint32_t g = hp[(size_t)myss[k] * 64 + lane];
            denom += w;
            a0 += w * bf2f(g & 0xffffu);
            a1 += w * bf2f(g >> 16);
        }
    } else {
        for (uint32_t k = 0; k < deg; ++k) {       // wave-uniform serial, filtered
            uint32_t s = edge_src[beg + k];
            if ((s / BROWS) == p) {
                float v = s_src[s] + sdj; v = v > 0.0f ? v : 0.01f * v;
                float w = __expf(v - m);
                uint32_t g = hp[(size_t)s * 64 + lane];
                denom += w;
                a0 += w * bf2f(g & 0xffffu);
                a1 += w * bf2f(g >> 16);
            }
        }
    }
    if (lane == 0) { part_m[pidx] = m; part_d[pidx] = denom; }
    // normalized bf16 partial (convex avg, O(1) magnitude -> rel err <= 2^-9);
    // nontemporal: don't evict the L2-resident source slice with the partial stream.
    float inv = 1.0f / denom;
    uint32_t packed = f2bf(a0 * inv) | (f2bf(a1 * inv) << 16);
    __builtin_nontemporal_store(packed, part_v + (size_t)pidx * 64 + (size_t)lane);
}

// ==== combine partials per dest (bf16 only): log-sum-exp merge of 4 buckets ====
__global__ __launch_bounds__(256) void pcomb_k(const void* __restrict__ h_sent,
                                               const void* __restrict__ h_type,
                                               const float* __restrict__ part_m,
                                               const float* __restrict__ part_d,
                                               const uint32_t* __restrict__ part_v,
                                               void* __restrict__ out) {
    bool isbf = detect_bf16((const uint32_t*)h_sent);
    if (!isbf) return;
    int j    = (blockIdx.x * 256 + (int)threadIdx.x) >> 6;
    int lane = threadIdx.x & 63;
    if (j >= N_TYPE) return;
    float dd[NBUCK], md[NBUCK];
#pragma unroll
    for (int p = 0; p < NBUCK; p++) dd[p] = part_d[j * NBUCK + p];
#pragma unroll
    for (int p = 0; p < NBUCK; p++) md[p] = part_m[j * NBUCK + p];
    float M = -INFINITY;
    bool any = false;
#pragma unroll
    for (int p = 0; p < NBUCK; p++)
        if (dd[p] > 0.0f) { M = fmaxf(M, md[p]); any = true; }
    if (!any) {   // isolated node keeps its input feature
        ((uint32_t*)out)[(size_t)j * 64 + lane] =
            ((const uint32_t*)h_type)[(size_t)j * 64 + lane];
        return;
    }
    uint32_t gv[NBUCK];
#pragma unroll
    for (int p = 0; p < NBUCK; p++)
        gv[p] = __builtin_nontemporal_load(part_v + ((size_t)(j * NBUCK + p) * 64
                                                     + (size_t)lane));
    float D = 0.0f, a0 = 0.0f, a1 = 0.0f;
#pragma unroll
    for (int p = 0; p < NBUCK; p++) {
        bool ok = dd[p] > 0.0f;
        float W = ok ? dd[p] * __expf(md[p] - M) : 0.0f;   // softmax mass of bucket p
        D += W;
        a0 += W * (ok ? bf2f(gv[p] & 0xffffu) : 0.0f);     // select guards garbage
        a1 += W * (ok ? bf2f(gv[p] >> 16)     : 0.0f);
    }
    float inv = 1.0f / D;
    ((uint32_t*)out)[(size_t)j * 64 + lane] = f2bf(a0 * inv) | (f2bf(a1 * inv) << 16);
}

// ---- old agg (round-8 best): f32 path + fallback when workspace too small ----
__global__ __launch_bounds__(256) void agg_k(const void* __restrict__ h_sent,
                                             const void* __restrict__ h_type,
                                             const float* __restrict__ s_src,
                                             const float* __restrict__ s_dst,
                                             const uint32_t* __restrict__ offsets,
                                             const uint32_t* __restrict__ edge_src,
                                             void* __restrict__ out,
                                             int use_part) {
    __shared__ float    sc[4][MAXDEG];
    __shared__ uint32_t ss[4][MAXDEG];
    bool isbf = detect_bf16((const uint32_t*)h_sent);
    if (use_part && isbf) return;        // bf16 handled by pagg+pcomb (uniform exit)
    int j     = (blockIdx.x * 256 + threadIdx.x) >> 6;
    int wslot = threadIdx.x >> 6;
    int lane  = threadIdx.x & 63;
    bool valid = j < N_TYPE;
    uint32_t beg = 0, deg = 0;
    float sdj = 0.0f;
    if (valid) {
        beg = offsets[j];
        deg = offsets[j + 1] - beg;
        sdj = s_dst[j];
    }
    float*    mysc = sc[wslot];
    uint32_t* myss = ss[wslot];
    bool fits = (deg <= MAXDEG);
    float m = -INFINITY;
    for (uint32_t k = lane; k < deg; k += 64) {
        uint32_t s = edge_src[beg + k];
        float v = s_src[s] + sdj;
        v = v > 0.0f ? v : 0.01f * v;
        if (fits) { mysc[k] = v; myss[k] = s; }
        m = fmaxf(m, v);
    }
#pragma unroll
    for (int off = 32; off; off >>= 1) m = fmaxf(m, __shfl_xor(m, off, 64));
    __syncthreads();
    if (!valid) return;
    if (deg == 0) {
        if (isbf) ((uint32_t*)out)[(size_t)j * 64 + lane] =
                      ((const uint32_t*)h_type)[(size_t)j * 64 + lane];
        else      ((float2*)out)[(size_t)j * 64 + lane] =
                      ((const float2*)h_type)[(size_t)j * 64 + lane];
        return;
    }
    float denom = 0.0f, a0 = 0.0f, a1 = 0.0f;
    if (isbf) {
        const uint32_t* hp = (const uint32_t*)h_sent;
        uint32_t k = 0;
        if (fits) {
            for (; k + 16 <= deg; k += 16) {
                uint32_t sv[16]; float vv[16]; uint32_t gv[16];
#pragma unroll
                for (int i = 0; i < 16; i++) { sv[i] = myss[k + i]; vv[i] = mysc[k + i]; }
#pragma unroll
                for (int i = 0; i < 16; i++) gv[i] = hp[(size_t)sv[i] * 64 + lane];
#pragma unroll
                for (int i = 0; i < 16; i++) {
                    float w = __expf(vv[i] - m);
                    denom += w;
                    a0 += w * bf2f(gv[i] & 0xffffu);
                    a1 += w * bf2f(gv[i] >> 16);
                }
            }
            for (; k + 8 <= deg; k += 8) {
                uint32_t sv[8]; float vv[8]; uint32_t gv[8];
#pragma unroll
                for (int i = 0; i < 8; i++) { sv[i] = myss[k + i]; vv[i] = mysc[k + i]; }
#pragma unroll
                for (int i = 0; i < 8; i++) gv[i] = hp[(size_t)sv[i] * 64 + lane];
#pragma unroll
                for (int i = 0; i < 8; i++) {
                    float w = __expf(vv[i] - m);
                    denom += w;
                    a0 += w * bf2f(gv[i] & 0xffffu);
                    a1 += w * bf2f(gv[i] >> 16);
                }
            }
            for (; k < deg; ++k) {
                float w = __expf(mysc[k] - m);
                uint32_t g = hp[(size_t)myss[k] * 64 + lane];
                denom += w;
                a0 += w * bf2f(g & 0xffffu);
                a1 += w * bf2f(g >> 16);
            }
        } else {
            for (k = 0; k < deg; ++k) {
                uint32_t s = edge_src[beg + k];
                float v = s_src[s] + sdj; v = v > 0.0f ? v : 0.01f * v;
                float w = __expf(v - m);
                uint32_t g = hp[(size_t)s * 64 + lane];
                denom += w;
                a0 += w * bf2f(g & 0xffffu);
                a1 += w * bf2f(g >> 16);
            }
        }
        float inv = 1.0f / denom;
        ((uint32_t*)out)[(size_t)j * 64 + lane] = f2bf(a0 * inv) | (f2bf(a1 * inv) << 16);
    } else {
        const float2* hp = (const float2*)h_sent;
        uint32_t k = 0;
        if (fits) {
            for (; k + 16 <= deg; k += 16) {
                uint32_t sv[16]; float vv[16]; float2 gv[16];
#pragma unroll
                for (int i = 0; i < 16; i++) { sv[i] = myss[k + i]; vv[i] = mysc[k + i]; }
#pragma unroll
                for (int i = 0; i < 16; i++) gv[i] = hp[(size_t)sv[i] * 64 + lane];
#pragma unroll
                for (int i = 0; i < 16; i++) {
                    float w = __expf(vv[i] - m);
                    denom += w;
                    a0 += w * gv[i].x;
                    a1 += w * gv[i].y;
                }
            }
            for (; k + 8 <= deg; k += 8) {
                uint32_t sv[8]; float vv[8]; float2 gv[8];
#pragma unroll
                for (int i = 0; i < 8; i++) { sv[i] = myss[k + i]; vv[i] = mysc[k + i]; }
#pragma unroll
                for (int i = 0; i < 8; i++) gv[i] = hp[(size_t)sv[i] * 64 + lane];
#pragma unroll
                for (int i = 0; i < 8; i++) {
                    float w = __expf(vv[i] - m);
                    denom += w;
                    a0 += w * gv[i].x;
                    a1 += w * gv[i].y;
                }
            }
            for (; k < deg; ++k) {
                float w = __expf(mysc[k] - m);
                float2 g = hp[(size_t)myss[k] * 64 + lane];
                denom += w;
                a0 += w * g.x;
                a1 += w * g.y;
            }
        } else {
            for (k = 0; k < deg; ++k) {
                uint32_t s = edge_src[beg + k];
                float v = s_src[s] + sdj; v = v > 0.0f ? v : 0.01f * v;
                float w = __expf(v - m);
                float2 g = hp[(size_t)s * 64 + lane];
                denom += w;
                a0 += w * g.x;
                a1 += w * g.y;
            }
        }
        float inv = 1.0f / denom;
        ((float2*)out)[(size_t)j * 64 + lane] = make_float2(a0 * inv, a1 * inv);
    }
}

static inline size_t align_up(size_t x) { return (x + 255) & ~(size_t)255; }

extern "C" void kernel_launch(void* const* d_in, const int* in_sizes, int n_in,
                              void* d_out, int out_size, void* d_ws, size_t ws_size,
                              hipStream_t stream) {
    const void* h_sent = d_in[0];
    const void* h_type = d_in[1];
    const void* attn_w = d_in[2];
    const int* src_idx = (const int*)d_in[3];
    const int* dst_idx = (const int*)d_in[4];

    // Live-set buffers first; then a REGION aliased between count2 (dead after fill_k)
    // and the partial buffers (born at pagg_k). Sequential stream -> no race.
    char* w = (char*)d_ws;
    float*    s_src     = (float*)w;    w += align_up((size_t)N_SENT * 4);
    float*    s_dst     = (float*)w;    w += align_up((size_t)N_TYPE * 4);
    uint32_t* total     = (uint32_t*)w; w += align_up((size_t)N_TYPE * 4);
    uint32_t* offsets   = (uint32_t*)w; w += align_up((size_t)(N_TYPE + 1) * 4);
    uint32_t* edge_src  = (uint32_t*)w; w += align_up((size_t)NEDGE * 4);
    char* region = w;
    uint32_t* count2 = (uint32_t*)region;                       // 10.24 MB during CSR build
    size_t count2_sz = align_up((size_t)HB * N_TYPE * 4);
    float*    part_m = (float*)region;
    float*    part_d = (float*)(region + align_up((size_t)N_TYPE * NBUCK * 4));
    uint32_t* part_v = (uint32_t*)(region + 2 * align_up((size_t)N_TYPE * NBUCK * 4));
    size_t part_sz = 2 * align_up((size_t)N_TYPE * NBUCK * 4)
                   + align_up((size_t)N_TYPE * NBUCK * 64 * 4);  // 10.56 MB (bf16 packed)
    size_t base = (size_t)(region - (char*)d_ws);
    size_t region_sz = count2_sz > part_sz ? count2_sz : part_sz;
    int use_part = (base + region_sz <= ws_size) ? 1 : 0;       // ~13.67 MB total

    scores_k<<<SC_BLOCKS, 256, 0, stream>>>(h_sent, h_type, attn_w, s_src, s_dst);
    count_k<<<HB, 256, 0, stream>>>(dst_idx, count2);
    sumscan_k<<<(N_TYPE * 8 + 255) / 256, 256, 0, stream>>>(count2, total);
    scan_k<<<1, 1024, 0, stream>>>(total, offsets);
    fill_k<<<HB, 256, 0, stream>>>(src_idx, dst_idx, offsets, count2, edge_src);
    if (use_part) {
        pagg_k<<<(N_TYPE / 4) * NBUCK, 256, 0, stream>>>(h_sent, s_src, s_dst,
                                                         offsets, edge_src,
                                                         part_m, part_d, part_v);
        pcomb_k<<<(N_TYPE + 3) / 4, 256, 0, stream>>>(h_sent, h_type,
                                                      part_m, part_d, part_v, d_out);
    }
    agg_k<<<(N_TYPE + 3) / 4, 256, 0, stream>>>(h_sent, h_type, s_src, s_dst,
                                                offsets, edge_src, d_out, use_part);
}